// Round 4
// baseline (302.408 us; speedup 1.0000x reference)
//
#include <hip/hip_runtime.h>
#include <hip/hip_bf16.h>

#define HID 128
#define NNODES 50000
#define NEDGES 800000
#define NGRAPHS 64
#define BN_EPS 1e-5f
#define CAP 64  // bucket capacity; deg ~ Poisson(16), P(deg>63) ~ 1e-21

typedef __attribute__((ext_vector_type(8))) short short8;   // 8 bf16 (4 VGPRs)
typedef __attribute__((ext_vector_type(4))) float f32x4;    // MFMA acc

static __device__ __forceinline__ unsigned short f2bf(float v) {
  __hip_bfloat16 b = __float2bfloat16(v);  // round-to-nearest
  return *reinterpret_cast<unsigned short*>(&b);
}
static __device__ __forceinline__ float bf2f(unsigned short u) {
  return __uint_as_float(((unsigned)u) << 16);
}
static __device__ __forceinline__ float lo16f(unsigned u) {
  return __uint_as_float(u << 16);
}
static __device__ __forceinline__ float hi16f(unsigned u) {
  return __uint_as_float(u & 0xFFFF0000u);
}

// pack fp32 -> (hi bf16 | lo bf16 << 16) in one u32 (bf16x3 split)
static __device__ __forceinline__ unsigned packhl(float v) {
  unsigned short h = f2bf(v);
  unsigned short l = f2bf(v - bf2f(h));
  return (unsigned)h | ((unsigned)l << 16);
}
// reconstruct fp32 from packed (hi + lo)
static __device__ __forceinline__ float upk(unsigned p) {
  return __uint_as_float(p << 16) + __uint_as_float(p & 0xFFFF0000u);
}
// 8 packed u32 -> hi/lo short8 fragments
static __device__ __forceinline__ void unpack8(uint4 wa, uint4 wb,
                                               short8& hi, short8& lo) {
  union U { unsigned u[4]; short8 s; };
  U H, L;
  unsigned w[8] = {wa.x, wa.y, wa.z, wa.w, wb.x, wb.y, wb.z, wb.w};
  #pragma unroll
  for (int t = 0; t < 4; t++) {
    unsigned a = w[2 * t], b = w[2 * t + 1];
    H.u[t] = (a & 0xFFFFu) | (b << 16);
    L.u[t] = (a >> 16) | (b & 0xFFFF0000u);
  }
  hi = H.s; lo = L.s;
}

// ===========================================================================
// prep: xbf = bf16(node_emb[x_idx]) + bucket-CSR build + weight pack +
// global L0 message table msgTg[76][64] (bf16x2: relu(node_emb[t]+edge_emb[a])).
//   eout[dst*CAP+pos] = src | attr<<16 | type<<18   (23 bits used)
// ===========================================================================
__global__ __launch_bounds__(256) void prep_kernel(
    const int* __restrict__ x_idx, const float* __restrict__ node_emb,
    unsigned int* __restrict__ xb2, const int* __restrict__ eidx,
    const int* __restrict__ eattr, int* __restrict__ cnt,
    int* __restrict__ eout, const float* __restrict__ W1,
    const float* __restrict__ W2, unsigned short* __restrict__ Wpk,
    unsigned* __restrict__ msgTg, const float* __restrict__ edge_emb) {
  int i = blockIdx.x * 256 + threadIdx.x;
  int stride = gridDim.x * 256;
  const float2* ne2 = (const float2*)node_emb;
  for (int t = i; t < NNODES * (HID / 2); t += stride) {
    int n = t >> 6;  // HID/2 == 64
    int c2 = t & 63;
    float2 v = ne2[x_idx[n] * 64 + c2];
    xb2[t] = (unsigned)f2bf(v.x) | ((unsigned)f2bf(v.y) << 16);
  }
  for (int e = i; e < NEDGES; e += stride) {
    int s = eidx[e];
    int d = eidx[NEDGES + e];
    int ty = x_idx[s];  // 0..18, L2-resident table
    int pos = atomicAdd(&cnt[d], 1);
    if (pos < CAP)
      eout[((size_t)d << 6) + pos] = s | (eattr[e] << 16) | (ty << 18);
  }
  for (int idx = i; idx < 76 * 64; idx += stride) {
    int combo = idx >> 6, c2 = (idx & 63) << 1;
    int ty = combo >> 2, at = combo & 3;
    float a0 = fmaxf(node_emb[ty * HID + c2] + edge_emb[at * HID + c2], 0.f);
    float a1 = fmaxf(node_emb[ty * HID + c2 + 1] + edge_emb[at * HID + c2 + 1], 0.f);
    msgTg[idx] = (unsigned)f2bf(a0) | ((unsigned)f2bf(a1) << 16);
  }
  for (int idx = i; idx < 65536; idx += stride) {
    int j = idx & 7;
    int l = (idx >> 3) & 63;
    int q = (idx >> 9) & 3;
    int t = (idx >> 11) & 7;
    int m = idx >> 14;
    int k = ((l >> 4) << 3) + j + (q << 5);
    int n = (t << 4) + (l & 15);
    int layer = m >> 1;
    const float* W = (m & 1) ? W2 : W1;
    float w = W[(size_t)layer * HID * HID + k * HID + n];
    unsigned short h = f2bf(w);
    Wpk[idx] = h;
    Wpk[idx + 65536] = f2bf(w - bf2f(h));
  }
}

// ===========================================================================
// Fused GINE layer, templated on L0.
// NT=48 nodes/block -> 1042 blocks = 4.07/CU: all blocks co-resident
// (4 x 8 waves = 32 waves/CU), single round, no half-occupancy tail.
// Gather: one edge row = whole wave (lane owns channels 2*lane, 2*lane+1);
// edge words broadcast via readlane; 2-strip x 8-edge software pipeline.
// L0: messages from global table msgTg[76][64] (L1/L2-resident broadcast).
// L1: row gather from in_bf, BN affine folded into fma (sheL = sh + emb).
// GEMM: wave = 16-ch tile x 3 row-tiles, 16x16x32 bf16 MFMA, hi/lo split.
// Epilogue: first 256 threads (thread = channel, 24 nodes each), stats
// atomics halved via LDS partial combine.
// ===========================================================================
#define NT 48
#define LDAF 132    // 128+4 u32: 16B-aligned rows
#define GRID_GINE ((NNODES + NT - 1) / NT)  // 1042

template <bool L0>
__global__ __launch_bounds__(512, 8) void gine_mlp_kernel(
    const unsigned short* __restrict__ in_bf,
    const float* __restrict__ instats,
    const float* __restrict__ gam, const float* __restrict__ bet,
    const int* __restrict__ cnt, const int* __restrict__ eout,
    const unsigned* __restrict__ msgTg, const float* __restrict__ edge_emb,
    const short8* __restrict__ Wh, const short8* __restrict__ Wl,
    const float* __restrict__ b1, const float* __restrict__ b2,
    unsigned short* __restrict__ out_bf, float* __restrict__ stats,
    const int* __restrict__ batch, float* __restrict__ gpool) {
  extern __shared__ __align__(16) char smem[];
  unsigned* hAp = (unsigned*)smem;                       // NT*LDAF packed
  float* sheL = (float*)(smem + NT * LDAF * 4);          // L1: 4*HID f32
  float* red = (float*)(smem + NT * LDAF * 4);           // epilogue scratch

  const int tid = threadIdx.x;
  const int lane = tid & 63;
  const int wave = tid >> 6;   // 0..7
  const int base = blockIdx.x * NT;

  float scl_lo = 1.0f, scl_hi = 1.0f, sh_lo = 0.0f, sh_hi = 0.0f;

  if constexpr (!L0) {
    // ---- she table (BN shift of previous layer folded into edge emb) ----
    if (tid < 4 * HID) {
      int c = tid & 127;
      float mu = instats[c] * (1.0f / NNODES);
      float var = instats[HID + c] * (1.0f / NNODES) - mu * mu;
      float s = gam[c] * rsqrtf(var + BN_EPS);
      float shc = bet[c] - mu * s;
      sheL[tid] = shc + edge_emb[tid];
    }
    // ---- per-lane affine for channels 2*lane, 2*lane+1 ----
    {
      int c0 = lane << 1;
      float mu0 = instats[c0] * (1.0f / NNODES);
      float var0 = instats[HID + c0] * (1.0f / NNODES) - mu0 * mu0;
      scl_lo = gam[c0] * rsqrtf(var0 + BN_EPS);
      sh_lo = bet[c0] - mu0 * scl_lo;
      float mu1 = instats[c0 + 1] * (1.0f / NNODES);
      float var1 = instats[HID + c0 + 1] * (1.0f / NNODES) - mu1 * mu1;
      scl_hi = gam[c0 + 1] * rsqrtf(var1 + BN_EPS);
      sh_hi = bet[c0 + 1] - mu1 * scl_hi;
    }
    __syncthreads();  // sheL ready
  }

  // ---- phase 1: gather (wave-per-edge-row, 6 nodes per wave) ----
  {
    const unsigned* in4 = (const unsigned*)in_bf;  // row = 64 u32
    int node0 = base + wave * 6;
    float acc0[6], acc1[6];
    #pragma unroll
    for (int i = 0; i < 6; i++) { acc0[i] = 0.0f; acc1[i] = 0.0f; }

    // hoisted: deg (SGPR), ep row, self row for all 6 nodes
    int dg6[6], epw6[6];
    unsigned sv6[6];
    #pragma unroll
    for (int i = 0; i < 6; i++) {
      int node = node0 + i;
      bool v = node < NNODES;
      dg6[i] = v ? __builtin_amdgcn_readfirstlane(min(cnt[node], CAP)) : 0;
      epw6[i] = v ? eout[(node << 6) + lane] : 0;
      sv6[i] = v ? in4[(node << 6) + lane] : 0u;
    }

// L1: issue strip of 8 x-rows; consume with folded-affine fma + relu + acc
#define GL_ISSUE(SB, X, A)                                      \
    {                                                           \
      _Pragma("unroll")                                         \
      for (int jj = 0; jj < 8; jj++) {                          \
        if ((SB) + jj < dg) {                                   \
          int w = __builtin_amdgcn_readlane(epw, (SB) + jj);    \
          A[jj] = (w >> 16) & 3;                                \
          X[jj] = in4[((w & 0xFFFF) << 6) + lane];              \
        }                                                       \
      }                                                         \
    }
#define GL_CONS(SB, X, A)                                       \
    {                                                           \
      _Pragma("unroll")                                         \
      for (int jj = 0; jj < 8; jj++) {                          \
        if ((SB) + jj < dg) {                                   \
          float2 e2 = *(const float2*)&sheL[(A[jj] << 7) + (lane << 1)]; \
          acc0[i] += fmaxf(fmaf(lo16f(X[jj]), scl_lo, e2.x), 0.0f); \
          acc1[i] += fmaxf(fmaf(hi16f(X[jj]), scl_hi, e2.y), 0.0f); \
        }                                                       \
      }                                                         \
    }
// L0: issue strip of 8 table rows (global, L1/L2-hit); consume = 2 adds
#define GT_ISSUE(SB, M)                                         \
    {                                                           \
      _Pragma("unroll")                                         \
      for (int jj = 0; jj < 8; jj++) {                          \
        if ((SB) + jj < dg) {                                   \
          int w = __builtin_amdgcn_readlane(epw, (SB) + jj);    \
          M[jj] = msgTg[(((w >> 16) & 127) << 6) + lane];       \
        }                                                       \
      }                                                         \
    }
#define GT_CONS(SB, M)                                          \
    {                                                           \
      _Pragma("unroll")                                         \
      for (int jj = 0; jj < 8; jj++) {                          \
        if ((SB) + jj < dg) {                                   \
          acc0[i] += lo16f(M[jj]);                              \
          acc1[i] += hi16f(M[jj]);                              \
        }                                                       \
      }                                                         \
    }

    #pragma unroll
    for (int i = 0; i < 6; i++) {
      int node = node0 + i;
      if (node >= NNODES) continue;  // uniform
      int dg = dg6[i];
      int epw = epw6[i];
      // self term
      if constexpr (L0) {
        acc0[i] = lo16f(sv6[i]);
        acc1[i] = hi16f(sv6[i]);
      } else {
        acc0[i] = fmaf(lo16f(sv6[i]), scl_lo, sh_lo);
        acc1[i] = fmaf(hi16f(sv6[i]), scl_hi, sh_hi);
      }
      if (dg > 0) {
        if constexpr (L0) {
          unsigned M0[8], M1[8];
          GT_ISSUE(0, M0);
          int s = 0;
          for (;;) {
            if (s * 8 + 8 < dg) GT_ISSUE(s * 8 + 8, M1);
            GT_CONS(s * 8, M0);
            s++;
            if (s * 8 >= dg) break;
            if (s * 8 + 8 < dg) GT_ISSUE(s * 8 + 8, M0);
            GT_CONS(s * 8, M1);
            s++;
            if (s * 8 >= dg) break;
          }
        } else {
          unsigned X0[8], X1[8];
          int A0[8], A1[8];
          GL_ISSUE(0, X0, A0);
          int s = 0;
          for (;;) {
            if (s * 8 + 8 < dg) GL_ISSUE(s * 8 + 8, X1, A1);
            GL_CONS(s * 8, X0, A0);
            s++;
            if (s * 8 >= dg) break;
            if (s * 8 + 8 < dg) GL_ISSUE(s * 8 + 8, X0, A0);
            GL_CONS(s * 8, X1, A1);
            s++;
            if (s * 8 >= dg) break;
          }
        }
      }
    }
#undef GL_ISSUE
#undef GL_CONS
#undef GT_ISSUE
#undef GT_CONS

    // write packed hi/lo rows (zeros for OOB rows -> GEMM reads no garbage)
    #pragma unroll
    for (int i = 0; i < 6; i++) {
      int nrow = wave * 6 + i;
      hAp[nrow * LDAF + (lane << 1)] = packhl(acc0[i]);
      hAp[nrow * LDAF + (lane << 1) + 1] = packhl(acc1[i]);
    }
  }
  __syncthreads();

  const int col = lane & 15;
  const int quad = lane >> 4;
  const int rbase = quad * 4;
  const int ch0 = wave * 16 + col;  // this wave's 16-channel tile
  const int aoff = quad * 8;

  // ---- phase 2: GEMM1 (hA @ W1 + b1, relu) -> back into hA ----
  {
    f32x4 a0 = {0.f, 0.f, 0.f, 0.f}, a1 = a0, a2 = a0;
    #pragma unroll
    for (int q = 0; q < 4; q++) {
      int f0 = wave * 256 + q * 64 + lane;
      short8 b0h = Wh[f0], b0l = Wl[f0];
      const unsigned* r0 = &hAp[col * LDAF + q * 32 + aoff];
      const unsigned* r1 = &hAp[(16 + col) * LDAF + q * 32 + aoff];
      const unsigned* r2 = &hAp[(32 + col) * LDAF + q * 32 + aoff];
      short8 a0h, a0l, a1h, a1l, a2h, a2l;
      unpack8(*(const uint4*)r0, *(const uint4*)(r0 + 4), a0h, a0l);
      unpack8(*(const uint4*)r1, *(const uint4*)(r1 + 4), a1h, a1l);
      unpack8(*(const uint4*)r2, *(const uint4*)(r2 + 4), a2h, a2l);
      a0 = __builtin_amdgcn_mfma_f32_16x16x32_bf16(a0h, b0h, a0, 0, 0, 0);
      a0 = __builtin_amdgcn_mfma_f32_16x16x32_bf16(a0l, b0h, a0, 0, 0, 0);
      a0 = __builtin_amdgcn_mfma_f32_16x16x32_bf16(a0h, b0l, a0, 0, 0, 0);
      a1 = __builtin_amdgcn_mfma_f32_16x16x32_bf16(a1h, b0h, a1, 0, 0, 0);
      a1 = __builtin_amdgcn_mfma_f32_16x16x32_bf16(a1l, b0h, a1, 0, 0, 0);
      a1 = __builtin_amdgcn_mfma_f32_16x16x32_bf16(a1h, b0l, a1, 0, 0, 0);
      a2 = __builtin_amdgcn_mfma_f32_16x16x32_bf16(a2h, b0h, a2, 0, 0, 0);
      a2 = __builtin_amdgcn_mfma_f32_16x16x32_bf16(a2l, b0h, a2, 0, 0, 0);
      a2 = __builtin_amdgcn_mfma_f32_16x16x32_bf16(a2h, b0l, a2, 0, 0, 0);
    }
    __syncthreads();  // all GEMM1 reads of hA complete
    float bb0 = b1[ch0];
    #pragma unroll
    for (int r = 0; r < 4; r++) {
      hAp[(rbase + r) * LDAF + ch0] = packhl(fmaxf(a0[r] + bb0, 0.0f));
      hAp[(16 + rbase + r) * LDAF + ch0] = packhl(fmaxf(a1[r] + bb0, 0.0f));
      hAp[(32 + rbase + r) * LDAF + ch0] = packhl(fmaxf(a2[r] + bb0, 0.0f));
    }
  }
  __syncthreads();

  // ---- phase 3: GEMM2 (h1 @ W2 + b2, relu) -> back into hA ----
  {
    f32x4 a0 = {0.f, 0.f, 0.f, 0.f}, a1 = a0, a2 = a0;
    #pragma unroll
    for (int q = 0; q < 4; q++) {
      int f0 = 2048 + wave * 256 + q * 64 + lane;  // gemm2 frags
      short8 b0h = Wh[f0], b0l = Wl[f0];
      const unsigned* r0 = &hAp[col * LDAF + q * 32 + aoff];
      const unsigned* r1 = &hAp[(16 + col) * LDAF + q * 32 + aoff];
      const unsigned* r2 = &hAp[(32 + col) * LDAF + q * 32 + aoff];
      short8 a0h, a0l, a1h, a1l, a2h, a2l;
      unpack8(*(const uint4*)r0, *(const uint4*)(r0 + 4), a0h, a0l);
      unpack8(*(const uint4*)r1, *(const uint4*)(r1 + 4), a1h, a1l);
      unpack8(*(const uint4*)r2, *(const uint4*)(r2 + 4), a2h, a2l);
      a0 = __builtin_amdgcn_mfma_f32_16x16x32_bf16(a0h, b0h, a0, 0, 0, 0);
      a0 = __builtin_amdgcn_mfma_f32_16x16x32_bf16(a0l, b0h, a0, 0, 0, 0);
      a0 = __builtin_amdgcn_mfma_f32_16x16x32_bf16(a0h, b0l, a0, 0, 0, 0);
      a1 = __builtin_amdgcn_mfma_f32_16x16x32_bf16(a1h, b0h, a1, 0, 0, 0);
      a1 = __builtin_amdgcn_mfma_f32_16x16x32_bf16(a1l, b0h, a1, 0, 0, 0);
      a1 = __builtin_amdgcn_mfma_f32_16x16x32_bf16(a1h, b0l, a1, 0, 0, 0);
      a2 = __builtin_amdgcn_mfma_f32_16x16x32_bf16(a2h, b0h, a2, 0, 0, 0);
      a2 = __builtin_amdgcn_mfma_f32_16x16x32_bf16(a2l, b0h, a2, 0, 0, 0);
      a2 = __builtin_amdgcn_mfma_f32_16x16x32_bf16(a2h, b0l, a2, 0, 0, 0);
    }
    __syncthreads();  // all GEMM2 reads complete
    float bb0 = b2[ch0];
    #pragma unroll
    for (int r = 0; r < 4; r++) {
      hAp[(rbase + r) * LDAF + ch0] = packhl(fmaxf(a0[r] + bb0, 0.0f));
      hAp[(16 + rbase + r) * LDAF + ch0] = packhl(fmaxf(a1[r] + bb0, 0.0f));
      hAp[(32 + rbase + r) * LDAF + ch0] = packhl(fmaxf(a2[r] + bb0, 0.0f));
    }
  }
  __syncthreads();

  // ---- phase 4: epilogue (h2 packed in hAp); first 256 threads compute ----
  float lsum = 0.0f, lsq = 0.0f;
  if (tid < 256) {
    const int c = tid & 127;
    const int yy = tid >> 7;
    if (out_bf) {
      #pragma unroll 4
      for (int i = 0; i < 24; i++) {
        int n = yy * 24 + i;
        int node = base + n;
        if (node < NNODES) {
          unsigned p = hAp[n * LDAF + c];
          out_bf[node * HID + c] = (unsigned short)(p & 0xFFFF);  // == f2bf(v)
          float v = upk(p);
          lsum += v;
          lsq += v * v;
        }
      }
    } else {
      int curg = -1;
      float pacc = 0.0f;
      for (int i = 0; i < 24; i++) {
        int n = yy * 24 + i;
        int node = base + n;
        if (node < NNODES) {
          float v = upk(hAp[n * LDAF + c]);
          lsum += v;
          lsq += v * v;
          int bg = batch[node];
          if (bg != curg) {
            if (curg >= 0) unsafeAtomicAdd(&gpool[curg * HID + c], pacc);
            curg = bg;
            pacc = 0.0f;
          }
          pacc += v;
        }
      }
      if (curg >= 0) unsafeAtomicAdd(&gpool[curg * HID + c], pacc);
    }
    if (tid >= 128) {  // stash yy=1 partials; combined below (halves atomics)
      red[tid - 128] = lsum;
      red[tid] = lsq;  // red[128..255]
    }
  }
  __syncthreads();
  if (tid < 128) {
    lsum += red[tid];
    lsq += red[128 + tid];
    unsafeAtomicAdd(&stats[tid], lsum);
    unsafeAtomicAdd(&stats[HID + tid], lsq);
  }
}

// ---------------------------------------------------------------------------
// out[g,c] = scl_c * gpool[g,c] + cnt_g * sh_c  (BN affine commutes with pool)
__device__ __forceinline__ int lbound(const int* __restrict__ arr, int n,
                                      int key) {
  int lo = 0, hi = n;
  while (lo < hi) {
    int mid = (lo + hi) >> 1;
    if (arr[mid] < key) lo = mid + 1; else hi = mid;
  }
  return lo;
}

__global__ __launch_bounds__(128) void finish_kernel(
    const float* __restrict__ gpool, const float* __restrict__ stats,
    const float* __restrict__ gam, const float* __restrict__ bet,
    const int* __restrict__ batch, float* __restrict__ out) {
  __shared__ int cnt_s;
  int g = blockIdx.x, c = threadIdx.x;
  if (c == 0)
    cnt_s = lbound(batch, NNODES, g + 1) - lbound(batch, NNODES, g);
  __syncthreads();
  float mu = stats[c] * (1.0f / NNODES);
  float var = stats[HID + c] * (1.0f / NNODES) - mu * mu;
  float scl = gam[c] * rsqrtf(var + BN_EPS);
  float sh = bet[c] - mu * scl;
  out[g * HID + c] = fmaf(gpool[g * HID + c], scl, (float)cnt_s * sh);
}

// ---------------------------------------------------------------------------
extern "C" void kernel_launch(void* const* d_in, const int* in_sizes, int n_in,
                              void* d_out, int out_size, void* d_ws, size_t ws_size,
                              hipStream_t stream) {
  const int* x_idx = (const int*)d_in[0];
  const int* eidx = (const int*)d_in[1];   // [2, E]: src row then dst row
  const int* eattr = (const int*)d_in[2];
  const int* batch = (const int*)d_in[3];
  const float* node_emb = (const float*)d_in[4];
  const float* edge_emb = (const float*)d_in[5];
  const float* W1 = (const float*)d_in[6];
  const float* b1 = (const float*)d_in[7];
  const float* W2 = (const float*)d_in[8];
  const float* b2 = (const float*)d_in[9];
  const float* bn_g = (const float*)d_in[10];
  const float* bn_b = (const float*)d_in[11];
  float* out = (float*)d_out;

  const size_t nfeat = (size_t)NNODES * HID;
  unsigned short* xbf = (unsigned short*)d_ws;  // [N,H] bf16
  unsigned short* h2bf = xbf + nfeat;           // [N,H] bf16
  float* stats0 = (float*)(h2bf + nfeat);       // [2,H]
  float* stats1 = stats0 + 2 * HID;             // [2,H]
  float* gpool = stats1 + 2 * HID;              // [G,H]
  int* cnt = (int*)(gpool + NGRAPHS * HID);     // [N]   (zeroed with stats)
  int* eout = cnt + NNODES;                     // [N*CAP]
  unsigned short* Wpk = (unsigned short*)(eout + (size_t)NNODES * CAP);
  unsigned* msgTg = (unsigned*)(Wpk + 131072);  // [76*64] bf16x2
  size_t needed = (size_t)((char*)(msgTg + 76 * 64) - (char*)d_ws);
  if (ws_size < needed) return;  // fails validation loudly, doesn't corrupt

  // zero stats0, stats1, gpool, cnt in one shot (contiguous)
  hipMemsetAsync(stats0, 0, (4 * HID + NGRAPHS * HID + NNODES) * sizeof(int),
                 stream);

  prep_kernel<<<1024, 256, 0, stream>>>(x_idx, node_emb, (unsigned int*)xbf,
                                        eidx, eattr, cnt, eout, W1, W2, Wpk,
                                        msgTg, edge_emb);

  const short8* Wfh = (const short8*)Wpk;  // 8192 frags (hi)
  const short8* Wfl = Wfh + 8192;          // 8192 frags (lo)
  const size_t smemsz = (size_t)NT * LDAF * 4 + 4 * HID * 4;  // hAp + sheL/red
  // layer 0: in = xbf, global msg-table fast path, out -> h2bf, stats0
  gine_mlp_kernel<true><<<GRID_GINE, 512, smemsz, stream>>>(
      xbf, nullptr, nullptr, nullptr, cnt, eout, msgTg, edge_emb,
      Wfh + 0 * 2048, Wfl + 0 * 2048, b1, b2, h2bf, stats0, nullptr, nullptr);
  // layer 1: in = h2bf with BN(layer0) folded, out -> gpool + stats1
  gine_mlp_kernel<false><<<GRID_GINE, 512, smemsz, stream>>>(
      h2bf, stats0, bn_g, bn_b, cnt, eout, msgTg, edge_emb,
      Wfh + 2 * 2048, Wfl + 2 * 2048, b1 + HID, b2 + HID, nullptr, stats1,
      batch, gpool);
  // final: out = scl*gpool + cnt*sh
  finish_kernel<<<NGRAPHS, 128, 0, stream>>>(gpool, stats1, bn_g + HID,
                                             bn_b + HID, batch, out);
}

// Round 5
// 275.267 us; speedup vs baseline: 1.0986x; 1.0986x over previous
//
#include <hip/hip_runtime.h>
#include <hip/hip_bf16.h>

#define HID 128
#define NNODES 50000
#define NEDGES 800000
#define NGRAPHS 64
#define BN_EPS 1e-5f
#define CAP 64  // bucket capacity; deg ~ Poisson(16), P(deg>63) ~ 1e-21

typedef __attribute__((ext_vector_type(8))) short short8;   // 8 bf16 (4 VGPRs)
typedef __attribute__((ext_vector_type(4))) float f32x4;    // MFMA acc

static __device__ __forceinline__ unsigned short f2bf(float v) {
  __hip_bfloat16 b = __float2bfloat16(v);  // round-to-nearest
  return *reinterpret_cast<unsigned short*>(&b);
}
static __device__ __forceinline__ float bf2f(unsigned short u) {
  return __uint_as_float(((unsigned)u) << 16);
}
static __device__ __forceinline__ float lo16f(unsigned u) {
  return __uint_as_float(u << 16);
}
static __device__ __forceinline__ float hi16f(unsigned u) {
  return __uint_as_float(u & 0xFFFF0000u);
}

// pack fp32 -> (hi bf16 | lo bf16 << 16) in one u32 (bf16x3 split)
static __device__ __forceinline__ unsigned packhl(float v) {
  unsigned short h = f2bf(v);
  unsigned short l = f2bf(v - bf2f(h));
  return (unsigned)h | ((unsigned)l << 16);
}
// reconstruct fp32 from packed (hi + lo)
static __device__ __forceinline__ float upk(unsigned p) {
  return __uint_as_float(p << 16) + __uint_as_float(p & 0xFFFF0000u);
}
// 8 packed u32 -> hi/lo short8 fragments
static __device__ __forceinline__ void unpack8(uint4 wa, uint4 wb,
                                               short8& hi, short8& lo) {
  union U { unsigned u[4]; short8 s; };
  U H, L;
  unsigned w[8] = {wa.x, wa.y, wa.z, wa.w, wb.x, wb.y, wb.z, wb.w};
  #pragma unroll
  for (int t = 0; t < 4; t++) {
    unsigned a = w[2 * t], b = w[2 * t + 1];
    H.u[t] = (a & 0xFFFFu) | (b << 16);
    L.u[t] = (a >> 16) | (b & 0xFFFF0000u);
  }
  hi = H.s; lo = L.s;
}

// ===========================================================================
// prep: bucket-CSR build + weight pack + L0 message table msgTg[76][64]
// (bf16x2 relu(node_emb[t]+edge_emb[a])) + L0 self table typeT[19][64].
// NOTE: no xbf materialization anymore -- L0 reads typeT[x_idx[node]].
//   eout[dst*CAP+pos] = src | attr<<16 | type<<18   (23 bits used)
// ===========================================================================
__global__ __launch_bounds__(256) void prep_kernel(
    const int* __restrict__ x_idx, const float* __restrict__ node_emb,
    const int* __restrict__ eidx, const int* __restrict__ eattr,
    int* __restrict__ cnt, int* __restrict__ eout,
    const float* __restrict__ W1, const float* __restrict__ W2,
    unsigned short* __restrict__ Wpk, unsigned* __restrict__ msgTg,
    unsigned* __restrict__ typeT, const float* __restrict__ edge_emb) {
  int i = blockIdx.x * 256 + threadIdx.x;
  int stride = gridDim.x * 256;
  for (int e = i; e < NEDGES; e += stride) {
    int s = eidx[e];
    int d = eidx[NEDGES + e];
    int ty = x_idx[s];  // 0..18, L2-resident table
    int pos = atomicAdd(&cnt[d], 1);
    if (pos < CAP)
      eout[((size_t)d << 6) + pos] = s | (eattr[e] << 16) | (ty << 18);
  }
  for (int idx = i; idx < 76 * 64; idx += stride) {
    int combo = idx >> 6, c2 = (idx & 63) << 1;
    int ty = combo >> 2, at = combo & 3;
    float a0 = fmaxf(node_emb[ty * HID + c2] + edge_emb[at * HID + c2], 0.f);
    float a1 = fmaxf(node_emb[ty * HID + c2 + 1] + edge_emb[at * HID + c2 + 1], 0.f);
    msgTg[idx] = (unsigned)f2bf(a0) | ((unsigned)f2bf(a1) << 16);
  }
  for (int idx = i; idx < 19 * 64; idx += stride) {
    int ty = idx >> 6, c2 = (idx & 63) << 1;
    typeT[idx] = (unsigned)f2bf(node_emb[ty * HID + c2]) |
                 ((unsigned)f2bf(node_emb[ty * HID + c2 + 1]) << 16);
  }
  for (int idx = i; idx < 65536; idx += stride) {
    int j = idx & 7;
    int l = (idx >> 3) & 63;
    int q = (idx >> 9) & 3;
    int t = (idx >> 11) & 7;
    int m = idx >> 14;
    int k = ((l >> 4) << 3) + j + (q << 5);
    int n = (t << 4) + (l & 15);
    int layer = m >> 1;
    const float* W = (m & 1) ? W2 : W1;
    float w = W[(size_t)layer * HID * HID + k * HID + n];
    unsigned short h = f2bf(w);
    Wpk[idx] = h;
    Wpk[idx + 65536] = f2bf(w - bf2f(h));
  }
}

// ===========================================================================
// Fused GINE layer, templated on L0. NT=32 (proven R3 geometry, no spill).
// Gather: one edge row = whole wave (lane owns channels 2*lane, 2*lane+1);
// edge words broadcast via readlane; 2-strip x 8-edge software pipeline.
// L0: messages from global msgTg[76][64]; self-term from typeT[x_idx[node]].
// L1: row gather from in_bf (h2bf), BN affine folded (sheL = sh + edge_emb).
// GEMM: wave = 16-ch tile x 2 row-tiles, 16x16x32 bf16 MFMA, hi/lo split.
// Epilogue: first 256 threads; stats atomics halved via LDS combine.
// ===========================================================================
#define NT 32
#define LDAF 132    // 128+4 u32: 16B-aligned rows
#define GRID_GINE ((NNODES + NT - 1) / NT)  // 1563

template <bool L0>
__global__ __launch_bounds__(512, 4) void gine_mlp_kernel(
    const unsigned short* __restrict__ in_bf,   // L0: typeT; L1: h2bf
    const int* __restrict__ xidx,               // L0 only
    const float* __restrict__ instats,
    const float* __restrict__ gam, const float* __restrict__ bet,
    const int* __restrict__ cnt, const int* __restrict__ eout,
    const unsigned* __restrict__ msgTg, const float* __restrict__ edge_emb,
    const short8* __restrict__ Wh, const short8* __restrict__ Wl,
    const float* __restrict__ b1, const float* __restrict__ b2,
    unsigned short* __restrict__ out_bf, float* __restrict__ stats,
    const int* __restrict__ batch, float* __restrict__ gpool) {
  extern __shared__ __align__(16) char smem[];
  unsigned* hAp = (unsigned*)smem;                       // NT*LDAF packed
  float* sheL = (float*)(smem + NT * LDAF * 4);          // L1: 4*HID f32
  float* red = (float*)(smem + NT * LDAF * 4);           // epilogue scratch

  const int tid = threadIdx.x;
  const int lane = tid & 63;
  const int wave = tid >> 6;   // 0..7
  const int base = blockIdx.x * NT;

  float scl_lo = 1.0f, scl_hi = 1.0f, sh_lo = 0.0f, sh_hi = 0.0f;

  if constexpr (!L0) {
    // ---- she table (BN shift of previous layer folded into edge emb) ----
    if (tid < 4 * HID) {
      int c = tid & 127;
      float mu = instats[c] * (1.0f / NNODES);
      float var = instats[HID + c] * (1.0f / NNODES) - mu * mu;
      float s = gam[c] * rsqrtf(var + BN_EPS);
      float shc = bet[c] - mu * s;
      sheL[tid] = shc + edge_emb[tid];
    }
    // ---- per-lane affine for channels 2*lane, 2*lane+1 ----
    {
      int c0 = lane << 1;
      float mu0 = instats[c0] * (1.0f / NNODES);
      float var0 = instats[HID + c0] * (1.0f / NNODES) - mu0 * mu0;
      scl_lo = gam[c0] * rsqrtf(var0 + BN_EPS);
      sh_lo = bet[c0] - mu0 * scl_lo;
      float mu1 = instats[c0 + 1] * (1.0f / NNODES);
      float var1 = instats[HID + c0 + 1] * (1.0f / NNODES) - mu1 * mu1;
      scl_hi = gam[c0 + 1] * rsqrtf(var1 + BN_EPS);
      sh_hi = bet[c0 + 1] - mu1 * scl_hi;
    }
    __syncthreads();  // sheL ready
  }

  // ---- phase 1: gather (wave-per-edge-row, 4 nodes per wave) ----
  {
    const unsigned* in4 = (const unsigned*)in_bf;  // row = 64 u32
    int node0 = base + wave * 4;
    float acc0[4], acc1[4];
    #pragma unroll
    for (int i = 0; i < 4; i++) { acc0[i] = 0.0f; acc1[i] = 0.0f; }

    // hoisted: deg (SGPR), ep row, self row for all 4 nodes
    int dg4[4], epw4[4];
    unsigned sv4[4];
    #pragma unroll
    for (int i = 0; i < 4; i++) {
      int node = node0 + i;
      bool v = node < NNODES;
      dg4[i] = v ? __builtin_amdgcn_readfirstlane(min(cnt[node], CAP)) : 0;
      epw4[i] = v ? eout[(node << 6) + lane] : 0;
      int srow;
      if constexpr (L0)
        srow = v ? __builtin_amdgcn_readfirstlane(xidx[node]) : 0;
      else
        srow = node;
      sv4[i] = v ? in4[(srow << 6) + lane] : 0u;
    }

// L1: issue strip of 8 x-rows; consume with folded-affine fma + relu + acc
#define GL_ISSUE(SB, X, A)                                      \
    {                                                           \
      _Pragma("unroll")                                         \
      for (int jj = 0; jj < 8; jj++) {                          \
        if ((SB) + jj < dg) {                                   \
          int w = __builtin_amdgcn_readlane(epw, (SB) + jj);    \
          A[jj] = (w >> 16) & 3;                                \
          X[jj] = in4[((w & 0xFFFF) << 6) + lane];              \
        }                                                       \
      }                                                         \
    }
#define GL_CONS(SB, X, A)                                       \
    {                                                           \
      _Pragma("unroll")                                         \
      for (int jj = 0; jj < 8; jj++) {                          \
        if ((SB) + jj < dg) {                                   \
          float2 e2 = *(const float2*)&sheL[(A[jj] << 7) + (lane << 1)]; \
          acc0[i] += fmaxf(fmaf(lo16f(X[jj]), scl_lo, e2.x), 0.0f); \
          acc1[i] += fmaxf(fmaf(hi16f(X[jj]), scl_hi, e2.y), 0.0f); \
        }                                                       \
      }                                                         \
    }
// L0: issue strip of 8 table rows (global, L1/L2-hit); consume = 2 adds
#define GT_ISSUE(SB, M)                                         \
    {                                                           \
      _Pragma("unroll")                                         \
      for (int jj = 0; jj < 8; jj++) {                          \
        if ((SB) + jj < dg) {                                   \
          int w = __builtin_amdgcn_readlane(epw, (SB) + jj);    \
          M[jj] = msgTg[(((w >> 16) & 127) << 6) + lane];       \
        }                                                       \
      }                                                         \
    }
#define GT_CONS(SB, M)                                          \
    {                                                           \
      _Pragma("unroll")                                         \
      for (int jj = 0; jj < 8; jj++) {                          \
        if ((SB) + jj < dg) {                                   \
          acc0[i] += lo16f(M[jj]);                              \
          acc1[i] += hi16f(M[jj]);                              \
        }                                                       \
      }                                                         \
    }

    #pragma unroll
    for (int i = 0; i < 4; i++) {
      int node = node0 + i;
      if (node >= NNODES) continue;  // uniform
      int dg = dg4[i];
      int epw = epw4[i];
      // self term
      if constexpr (L0) {
        acc0[i] = lo16f(sv4[i]);
        acc1[i] = hi16f(sv4[i]);
      } else {
        acc0[i] = fmaf(lo16f(sv4[i]), scl_lo, sh_lo);
        acc1[i] = fmaf(hi16f(sv4[i]), scl_hi, sh_hi);
      }
      if (dg > 0) {
        if constexpr (L0) {
          unsigned M0[8], M1[8];
          GT_ISSUE(0, M0);
          int s = 0;
          for (;;) {
            if (s * 8 + 8 < dg) GT_ISSUE(s * 8 + 8, M1);
            GT_CONS(s * 8, M0);
            s++;
            if (s * 8 >= dg) break;
            if (s * 8 + 8 < dg) GT_ISSUE(s * 8 + 8, M0);
            GT_CONS(s * 8, M1);
            s++;
            if (s * 8 >= dg) break;
          }
        } else {
          unsigned X0[8], X1[8];
          int A0[8], A1[8];
          GL_ISSUE(0, X0, A0);
          int s = 0;
          for (;;) {
            if (s * 8 + 8 < dg) GL_ISSUE(s * 8 + 8, X1, A1);
            GL_CONS(s * 8, X0, A0);
            s++;
            if (s * 8 >= dg) break;
            if (s * 8 + 8 < dg) GL_ISSUE(s * 8 + 8, X0, A0);
            GL_CONS(s * 8, X1, A1);
            s++;
            if (s * 8 >= dg) break;
          }
        }
      }
    }
#undef GL_ISSUE
#undef GL_CONS
#undef GT_ISSUE
#undef GT_CONS

    // write packed hi/lo rows (zeros for OOB rows -> GEMM reads no garbage)
    #pragma unroll
    for (int i = 0; i < 4; i++) {
      int nrow = wave * 4 + i;
      hAp[nrow * LDAF + (lane << 1)] = packhl(acc0[i]);
      hAp[nrow * LDAF + (lane << 1) + 1] = packhl(acc1[i]);
    }
  }
  __syncthreads();

  const int col = lane & 15;
  const int quad = lane >> 4;
  const int rbase = quad * 4;
  const int ch0 = wave * 16 + col;  // this wave's 16-channel tile
  const int aoff = quad * 8;

  // ---- phase 2: GEMM1 (hA @ W1 + b1, relu) -> back into hA ----
  {
    f32x4 a0 = {0.f, 0.f, 0.f, 0.f}, a1 = a0;
    #pragma unroll
    for (int q = 0; q < 4; q++) {
      int f0 = wave * 256 + q * 64 + lane;
      short8 b0h = Wh[f0], b0l = Wl[f0];
      const unsigned* r0 = &hAp[col * LDAF + q * 32 + aoff];
      const unsigned* r1 = &hAp[(16 + col) * LDAF + q * 32 + aoff];
      short8 a0h, a0l, a1h, a1l;
      unpack8(*(const uint4*)r0, *(const uint4*)(r0 + 4), a0h, a0l);
      unpack8(*(const uint4*)r1, *(const uint4*)(r1 + 4), a1h, a1l);
      a0 = __builtin_amdgcn_mfma_f32_16x16x32_bf16(a0h, b0h, a0, 0, 0, 0);
      a0 = __builtin_amdgcn_mfma_f32_16x16x32_bf16(a0l, b0h, a0, 0, 0, 0);
      a0 = __builtin_amdgcn_mfma_f32_16x16x32_bf16(a0h, b0l, a0, 0, 0, 0);
      a1 = __builtin_amdgcn_mfma_f32_16x16x32_bf16(a1h, b0h, a1, 0, 0, 0);
      a1 = __builtin_amdgcn_mfma_f32_16x16x32_bf16(a1l, b0h, a1, 0, 0, 0);
      a1 = __builtin_amdgcn_mfma_f32_16x16x32_bf16(a1h, b0l, a1, 0, 0, 0);
    }
    __syncthreads();  // all GEMM1 reads of hA complete
    float bb0 = b1[ch0];
    #pragma unroll
    for (int r = 0; r < 4; r++) {
      hAp[(rbase + r) * LDAF + ch0] = packhl(fmaxf(a0[r] + bb0, 0.0f));
      hAp[(16 + rbase + r) * LDAF + ch0] = packhl(fmaxf(a1[r] + bb0, 0.0f));
    }
  }
  __syncthreads();

  // ---- phase 3: GEMM2 (h1 @ W2 + b2, relu) -> back into hA ----
  {
    f32x4 a0 = {0.f, 0.f, 0.f, 0.f}, a1 = a0;
    #pragma unroll
    for (int q = 0; q < 4; q++) {
      int f0 = 2048 + wave * 256 + q * 64 + lane;  // gemm2 frags
      short8 b0h = Wh[f0], b0l = Wl[f0];
      const unsigned* r0 = &hAp[col * LDAF + q * 32 + aoff];
      const unsigned* r1 = &hAp[(16 + col) * LDAF + q * 32 + aoff];
      short8 a0h, a0l, a1h, a1l;
      unpack8(*(const uint4*)r0, *(const uint4*)(r0 + 4), a0h, a0l);
      unpack8(*(const uint4*)r1, *(const uint4*)(r1 + 4), a1h, a1l);
      a0 = __builtin_amdgcn_mfma_f32_16x16x32_bf16(a0h, b0h, a0, 0, 0, 0);
      a0 = __builtin_amdgcn_mfma_f32_16x16x32_bf16(a0l, b0h, a0, 0, 0, 0);
      a0 = __builtin_amdgcn_mfma_f32_16x16x32_bf16(a0h, b0l, a0, 0, 0, 0);
      a1 = __builtin_amdgcn_mfma_f32_16x16x32_bf16(a1h, b0h, a1, 0, 0, 0);
      a1 = __builtin_amdgcn_mfma_f32_16x16x32_bf16(a1l, b0h, a1, 0, 0, 0);
      a1 = __builtin_amdgcn_mfma_f32_16x16x32_bf16(a1h, b0l, a1, 0, 0, 0);
    }
    __syncthreads();  // all GEMM2 reads complete
    float bb0 = b2[ch0];
    #pragma unroll
    for (int r = 0; r < 4; r++) {
      hAp[(rbase + r) * LDAF + ch0] = packhl(fmaxf(a0[r] + bb0, 0.0f));
      hAp[(16 + rbase + r) * LDAF + ch0] = packhl(fmaxf(a1[r] + bb0, 0.0f));
    }
  }
  __syncthreads();

  // ---- phase 4: epilogue (h2 packed in hAp); first 256 threads compute ----
  float lsum = 0.0f, lsq = 0.0f;
  if (tid < 256) {
    const int c = tid & 127;
    const int yy = tid >> 7;
    if (out_bf) {
      #pragma unroll 4
      for (int i = 0; i < 16; i++) {
        int n = yy * 16 + i;
        int node = base + n;
        if (node < NNODES) {
          unsigned p = hAp[n * LDAF + c];
          out_bf[node * HID + c] = (unsigned short)(p & 0xFFFF);  // == f2bf(v)
          float v = upk(p);
          lsum += v;
          lsq += v * v;
        }
      }
    } else {
      int curg = -1;
      float pacc = 0.0f;
      for (int i = 0; i < 16; i++) {
        int n = yy * 16 + i;
        int node = base + n;
        if (node < NNODES) {
          float v = upk(hAp[n * LDAF + c]);
          lsum += v;
          lsq += v * v;
          int bg = batch[node];
          if (bg != curg) {
            if (curg >= 0) unsafeAtomicAdd(&gpool[curg * HID + c], pacc);
            curg = bg;
            pacc = 0.0f;
          }
          pacc += v;
        }
      }
      if (curg >= 0) unsafeAtomicAdd(&gpool[curg * HID + c], pacc);
    }
    if (tid >= 128) {  // stash yy=1 partials; combined below (halves atomics)
      red[tid - 128] = lsum;
      red[tid] = lsq;  // red[128..255]
    }
  }
  __syncthreads();
  if (tid < 128) {
    lsum += red[tid];
    lsq += red[128 + tid];
    unsafeAtomicAdd(&stats[tid], lsum);
    unsafeAtomicAdd(&stats[HID + tid], lsq);
  }
}

// ---------------------------------------------------------------------------
// out[g,c] = scl_c * gpool[g,c] + cnt_g * sh_c  (BN affine commutes with pool)
__device__ __forceinline__ int lbound(const int* __restrict__ arr, int n,
                                      int key) {
  int lo = 0, hi = n;
  while (lo < hi) {
    int mid = (lo + hi) >> 1;
    if (arr[mid] < key) lo = mid + 1; else hi = mid;
  }
  return lo;
}

__global__ __launch_bounds__(128) void finish_kernel(
    const float* __restrict__ gpool, const float* __restrict__ stats,
    const float* __restrict__ gam, const float* __restrict__ bet,
    const int* __restrict__ batch, float* __restrict__ out) {
  __shared__ int cnt_s;
  int g = blockIdx.x, c = threadIdx.x;
  if (c == 0)
    cnt_s = lbound(batch, NNODES, g + 1) - lbound(batch, NNODES, g);
  __syncthreads();
  float mu = stats[c] * (1.0f / NNODES);
  float var = stats[HID + c] * (1.0f / NNODES) - mu * mu;
  float scl = gam[c] * rsqrtf(var + BN_EPS);
  float sh = bet[c] - mu * scl;
  out[g * HID + c] = fmaf(gpool[g * HID + c], scl, (float)cnt_s * sh);
}

// ---------------------------------------------------------------------------
extern "C" void kernel_launch(void* const* d_in, const int* in_sizes, int n_in,
                              void* d_out, int out_size, void* d_ws, size_t ws_size,
                              hipStream_t stream) {
  const int* x_idx = (const int*)d_in[0];
  const int* eidx = (const int*)d_in[1];   // [2, E]: src row then dst row
  const int* eattr = (const int*)d_in[2];
  const int* batch = (const int*)d_in[3];
  const float* node_emb = (const float*)d_in[4];
  const float* edge_emb = (const float*)d_in[5];
  const float* W1 = (const float*)d_in[6];
  const float* b1 = (const float*)d_in[7];
  const float* W2 = (const float*)d_in[8];
  const float* b2 = (const float*)d_in[9];
  const float* bn_g = (const float*)d_in[10];
  const float* bn_b = (const float*)d_in[11];
  float* out = (float*)d_out;

  const size_t nfeat = (size_t)NNODES * HID;
  unsigned short* h2bf = (unsigned short*)d_ws;  // [N,H] bf16
  float* stats0 = (float*)(h2bf + nfeat);        // [2,H]
  float* stats1 = stats0 + 2 * HID;              // [2,H]
  float* gpool = stats1 + 2 * HID;               // [G,H]
  int* cnt = (int*)(gpool + NGRAPHS * HID);      // [N]   (zeroed with stats)
  int* eout = cnt + NNODES;                      // [N*CAP]
  unsigned short* Wpk = (unsigned short*)(eout + (size_t)NNODES * CAP);
  unsigned* msgTg = (unsigned*)(Wpk + 131072);   // [76*64] bf16x2
  unsigned* typeT = msgTg + 76 * 64;             // [19*64] bf16x2
  size_t needed = (size_t)((char*)(typeT + 19 * 64) - (char*)d_ws);
  if (ws_size < needed) return;  // fails validation loudly, doesn't corrupt

  // zero stats0, stats1, gpool, cnt in one shot (contiguous)
  hipMemsetAsync(stats0, 0, (4 * HID + NGRAPHS * HID + NNODES) * sizeof(int),
                 stream);

  prep_kernel<<<1024, 256, 0, stream>>>(x_idx, node_emb, eidx, eattr, cnt,
                                        eout, W1, W2, Wpk, msgTg, typeT,
                                        edge_emb);

  const short8* Wfh = (const short8*)Wpk;  // 8192 frags (hi)
  const short8* Wfl = Wfh + 8192;          // 8192 frags (lo)
  const size_t smemsz = (size_t)NT * LDAF * 4 + 4 * HID * 4;  // hAp + sheL/red
  // layer 0: self from typeT[x_idx[node]], msgs from msgTg -> h2bf, stats0
  gine_mlp_kernel<true><<<GRID_GINE, 512, smemsz, stream>>>(
      (const unsigned short*)typeT, x_idx, nullptr, nullptr, nullptr, cnt,
      eout, msgTg, edge_emb, Wfh + 0 * 2048, Wfl + 0 * 2048, b1, b2, h2bf,
      stats0, nullptr, nullptr);
  // layer 1: in = h2bf with BN(layer0) folded, out -> gpool + stats1
  gine_mlp_kernel<false><<<GRID_GINE, 512, smemsz, stream>>>(
      h2bf, nullptr, stats0, bn_g, bn_b, cnt, eout, msgTg, edge_emb,
      Wfh + 2 * 2048, Wfl + 2 * 2048, b1 + HID, b2 + HID, nullptr, stats1,
      batch, gpool);
  // final: out = scl*gpool + cnt*sh
  finish_kernel<<<NGRAPHS, 128, 0, stream>>>(gpool, stats1, bn_g + HID,
                                             bn_b + HID, batch, out);
}

// Round 6
// 257.678 us; speedup vs baseline: 1.1736x; 1.0683x over previous
//
#include <hip/hip_runtime.h>
#include <hip/hip_bf16.h>

#define HID 128
#define NNODES 50000
#define NEDGES 800000
#define NGRAPHS 64
#define BN_EPS 1e-5f
#define CAP 64  // bucket capacity; deg ~ Poisson(16), P(deg>63) ~ 1e-21

typedef __attribute__((ext_vector_type(8))) short short8;   // 8 bf16 (4 VGPRs)
typedef __attribute__((ext_vector_type(4))) float f32x4;    // MFMA acc

static __device__ __forceinline__ unsigned short f2bf(float v) {
  __hip_bfloat16 b = __float2bfloat16(v);  // round-to-nearest
  return *reinterpret_cast<unsigned short*>(&b);
}
static __device__ __forceinline__ float bf2f(unsigned short u) {
  return __uint_as_float(((unsigned)u) << 16);
}
static __device__ __forceinline__ float lo16f(unsigned u) {
  return __uint_as_float(u << 16);
}
static __device__ __forceinline__ float hi16f(unsigned u) {
  return __uint_as_float(u & 0xFFFF0000u);
}

// pack fp32 -> (hi bf16 | lo bf16 << 16) in one u32 (bf16x3 split)
static __device__ __forceinline__ unsigned packhl(float v) {
  unsigned short h = f2bf(v);
  unsigned short l = f2bf(v - bf2f(h));
  return (unsigned)h | ((unsigned)l << 16);
}
// reconstruct fp32 from packed (hi + lo)
static __device__ __forceinline__ float upk(unsigned p) {
  return __uint_as_float(p << 16) + __uint_as_float(p & 0xFFFF0000u);
}
// 8 packed u32 -> hi/lo short8 fragments
static __device__ __forceinline__ void unpack8(uint4 wa, uint4 wb,
                                               short8& hi, short8& lo) {
  union U { unsigned u[4]; short8 s; };
  U H, L;
  unsigned w[8] = {wa.x, wa.y, wa.z, wa.w, wb.x, wb.y, wb.z, wb.w};
  #pragma unroll
  for (int t = 0; t < 4; t++) {
    unsigned a = w[2 * t], b = w[2 * t + 1];
    H.u[t] = (a & 0xFFFFu) | (b << 16);
    L.u[t] = (a >> 16) | (b & 0xFFFF0000u);
  }
  hi = H.s; lo = L.s;
}

// ===========================================================================
// prep: bucket-CSR build + weight pack + L0 message table msgTg[76][64]
// (bf16x2 relu(node_emb[t]+edge_emb[a])) + L0 self table typeT[19][64].
//   eout[dst*CAP+pos] = src | attr<<16 | type<<18   (23 bits used)
// ===========================================================================
__global__ __launch_bounds__(256) void prep_kernel(
    const int* __restrict__ x_idx, const float* __restrict__ node_emb,
    const int* __restrict__ eidx, const int* __restrict__ eattr,
    int* __restrict__ cnt, int* __restrict__ eout,
    const float* __restrict__ W1, const float* __restrict__ W2,
    unsigned short* __restrict__ Wpk, unsigned* __restrict__ msgTg,
    unsigned* __restrict__ typeT, const float* __restrict__ edge_emb) {
  int i = blockIdx.x * 256 + threadIdx.x;
  int stride = gridDim.x * 256;
  for (int e = i; e < NEDGES; e += stride) {
    int s = eidx[e];
    int d = eidx[NEDGES + e];
    int ty = x_idx[s];  // 0..18, L2-resident table
    int pos = atomicAdd(&cnt[d], 1);
    if (pos < CAP)
      eout[((size_t)d << 6) + pos] = s | (eattr[e] << 16) | (ty << 18);
  }
  for (int idx = i; idx < 76 * 64; idx += stride) {
    int combo = idx >> 6, c2 = (idx & 63) << 1;
    int ty = combo >> 2, at = combo & 3;
    float a0 = fmaxf(node_emb[ty * HID + c2] + edge_emb[at * HID + c2], 0.f);
    float a1 = fmaxf(node_emb[ty * HID + c2 + 1] + edge_emb[at * HID + c2 + 1], 0.f);
    msgTg[idx] = (unsigned)f2bf(a0) | ((unsigned)f2bf(a1) << 16);
  }
  for (int idx = i; idx < 19 * 64; idx += stride) {
    int ty = idx >> 6, c2 = (idx & 63) << 1;
    typeT[idx] = (unsigned)f2bf(node_emb[ty * HID + c2]) |
                 ((unsigned)f2bf(node_emb[ty * HID + c2 + 1]) << 16);
  }
  for (int idx = i; idx < 65536; idx += stride) {
    int j = idx & 7;
    int l = (idx >> 3) & 63;
    int q = (idx >> 9) & 3;
    int t = (idx >> 11) & 7;
    int m = idx >> 14;
    int k = ((l >> 4) << 3) + j + (q << 5);
    int n = (t << 4) + (l & 15);
    int layer = m >> 1;
    const float* W = (m & 1) ? W2 : W1;
    float w = W[(size_t)layer * HID * HID + k * HID + n];
    unsigned short h = f2bf(w);
    Wpk[idx] = h;
    Wpk[idx + 65536] = f2bf(w - bf2f(h));
  }
}

// ===========================================================================
// Fused GINE layer, templated on L0. NT=32 geometry (proven, no spill).
// __launch_bounds__(512, 8): 8 waves/EU -> 4 blocks/CU = 32 waves = 100%
// theoretical occupancy. (R3/R5's (512,4) requested only 2 blocks/CU = 50%
// -- the measured 45% occupancy was self-inflicted, not a resource limit.
// VGPR cap at 8 waves/EU is 64; this code measured 36, so no spill.)
// Gather: one edge row = whole wave (lane owns channels 2*lane, 2*lane+1);
// edge words broadcast via readlane; 2-strip x 8-edge software pipeline.
// L0: messages from global msgTg[76][64]; self-term from typeT[x_idx[node]].
// L1: row gather from in_bf (h2bf), BN affine folded (sheL = sh + edge_emb).
// GEMM: wave = 16-ch tile x 2 row-tiles, 16x16x32 bf16 MFMA, hi/lo split.
// Epilogue: first 256 threads; stats atomics halved via LDS combine.
// ===========================================================================
#define NT 32
#define LDAF 132    // 128+4 u32: 16B-aligned rows
#define GRID_GINE ((NNODES + NT - 1) / NT)  // 1563

template <bool L0>
__global__ __launch_bounds__(512, 8) void gine_mlp_kernel(
    const unsigned short* __restrict__ in_bf,   // L0: typeT; L1: h2bf
    const int* __restrict__ xidx,               // L0 only
    const float* __restrict__ instats,
    const float* __restrict__ gam, const float* __restrict__ bet,
    const int* __restrict__ cnt, const int* __restrict__ eout,
    const unsigned* __restrict__ msgTg, const float* __restrict__ edge_emb,
    const short8* __restrict__ Wh, const short8* __restrict__ Wl,
    const float* __restrict__ b1, const float* __restrict__ b2,
    unsigned short* __restrict__ out_bf, float* __restrict__ stats,
    const int* __restrict__ batch, float* __restrict__ gpool) {
  extern __shared__ __align__(16) char smem[];
  unsigned* hAp = (unsigned*)smem;                       // NT*LDAF packed
  float* sheL = (float*)(smem + NT * LDAF * 4);          // L1: 4*HID f32
  float* red = (float*)(smem + NT * LDAF * 4);           // epilogue scratch

  const int tid = threadIdx.x;
  const int lane = tid & 63;
  const int wave = tid >> 6;   // 0..7
  const int base = blockIdx.x * NT;

  float scl_lo = 1.0f, scl_hi = 1.0f, sh_lo = 0.0f, sh_hi = 0.0f;

  if constexpr (!L0) {
    // ---- she table (BN shift of previous layer folded into edge emb) ----
    if (tid < 4 * HID) {
      int c = tid & 127;
      float mu = instats[c] * (1.0f / NNODES);
      float var = instats[HID + c] * (1.0f / NNODES) - mu * mu;
      float s = gam[c] * rsqrtf(var + BN_EPS);
      float shc = bet[c] - mu * s;
      sheL[tid] = shc + edge_emb[tid];
    }
    // ---- per-lane affine for channels 2*lane, 2*lane+1 ----
    {
      int c0 = lane << 1;
      float mu0 = instats[c0] * (1.0f / NNODES);
      float var0 = instats[HID + c0] * (1.0f / NNODES) - mu0 * mu0;
      scl_lo = gam[c0] * rsqrtf(var0 + BN_EPS);
      sh_lo = bet[c0] - mu0 * scl_lo;
      float mu1 = instats[c0 + 1] * (1.0f / NNODES);
      float var1 = instats[HID + c0 + 1] * (1.0f / NNODES) - mu1 * mu1;
      scl_hi = gam[c0 + 1] * rsqrtf(var1 + BN_EPS);
      sh_hi = bet[c0 + 1] - mu1 * scl_hi;
    }
    __syncthreads();  // sheL ready
  }

  // ---- phase 1: gather (wave-per-edge-row, 4 nodes per wave) ----
  {
    const unsigned* in4 = (const unsigned*)in_bf;  // row = 64 u32
    int node0 = base + wave * 4;
    float acc0[4], acc1[4];
    #pragma unroll
    for (int i = 0; i < 4; i++) { acc0[i] = 0.0f; acc1[i] = 0.0f; }

    // hoisted: deg (SGPR), ep row, self row for all 4 nodes
    int dg4[4], epw4[4];
    unsigned sv4[4];
    #pragma unroll
    for (int i = 0; i < 4; i++) {
      int node = node0 + i;
      bool v = node < NNODES;
      dg4[i] = v ? __builtin_amdgcn_readfirstlane(min(cnt[node], CAP)) : 0;
      epw4[i] = v ? eout[(node << 6) + lane] : 0;
      int srow;
      if constexpr (L0)
        srow = v ? __builtin_amdgcn_readfirstlane(xidx[node]) : 0;
      else
        srow = node;
      sv4[i] = v ? in4[(srow << 6) + lane] : 0u;
    }

// L1: issue strip of 8 x-rows; consume with folded-affine fma + relu + acc
#define GL_ISSUE(SB, X, A)                                      \
    {                                                           \
      _Pragma("unroll")                                         \
      for (int jj = 0; jj < 8; jj++) {                          \
        if ((SB) + jj < dg) {                                   \
          int w = __builtin_amdgcn_readlane(epw, (SB) + jj);    \
          A[jj] = (w >> 16) & 3;                                \
          X[jj] = in4[((w & 0xFFFF) << 6) + lane];              \
        }                                                       \
      }                                                         \
    }
#define GL_CONS(SB, X, A)                                       \
    {                                                           \
      _Pragma("unroll")                                         \
      for (int jj = 0; jj < 8; jj++) {                          \
        if ((SB) + jj < dg) {                                   \
          float2 e2 = *(const float2*)&sheL[(A[jj] << 7) + (lane << 1)]; \
          acc0[i] += fmaxf(fmaf(lo16f(X[jj]), scl_lo, e2.x), 0.0f); \
          acc1[i] += fmaxf(fmaf(hi16f(X[jj]), scl_hi, e2.y), 0.0f); \
        }                                                       \
      }                                                         \
    }
// L0: issue strip of 8 table rows (global, L1/L2-hit); consume = 2 adds
#define GT_ISSUE(SB, M)                                         \
    {                                                           \
      _Pragma("unroll")                                         \
      for (int jj = 0; jj < 8; jj++) {                          \
        if ((SB) + jj < dg) {                                   \
          int w = __builtin_amdgcn_readlane(epw, (SB) + jj);    \
          M[jj] = msgTg[(((w >> 16) & 127) << 6) + lane];       \
        }                                                       \
      }                                                         \
    }
#define GT_CONS(SB, M)                                          \
    {                                                           \
      _Pragma("unroll")                                         \
      for (int jj = 0; jj < 8; jj++) {                          \
        if ((SB) + jj < dg) {                                   \
          acc0[i] += lo16f(M[jj]);                              \
          acc1[i] += hi16f(M[jj]);                              \
        }                                                       \
      }                                                         \
    }

    #pragma unroll
    for (int i = 0; i < 4; i++) {
      int node = node0 + i;
      if (node >= NNODES) continue;  // uniform
      int dg = dg4[i];
      int epw = epw4[i];
      // self term
      if constexpr (L0) {
        acc0[i] = lo16f(sv4[i]);
        acc1[i] = hi16f(sv4[i]);
      } else {
        acc0[i] = fmaf(lo16f(sv4[i]), scl_lo, sh_lo);
        acc1[i] = fmaf(hi16f(sv4[i]), scl_hi, sh_hi);
      }
      if (dg > 0) {
        if constexpr (L0) {
          unsigned M0[8], M1[8];
          GT_ISSUE(0, M0);
          int s = 0;
          for (;;) {
            if (s * 8 + 8 < dg) GT_ISSUE(s * 8 + 8, M1);
            GT_CONS(s * 8, M0);
            s++;
            if (s * 8 >= dg) break;
            if (s * 8 + 8 < dg) GT_ISSUE(s * 8 + 8, M0);
            GT_CONS(s * 8, M1);
            s++;
            if (s * 8 >= dg) break;
          }
        } else {
          unsigned X0[8], X1[8];
          int A0[8], A1[8];
          GL_ISSUE(0, X0, A0);
          int s = 0;
          for (;;) {
            if (s * 8 + 8 < dg) GL_ISSUE(s * 8 + 8, X1, A1);
            GL_CONS(s * 8, X0, A0);
            s++;
            if (s * 8 >= dg) break;
            if (s * 8 + 8 < dg) GL_ISSUE(s * 8 + 8, X0, A0);
            GL_CONS(s * 8, X1, A1);
            s++;
            if (s * 8 >= dg) break;
          }
        }
      }
    }
#undef GL_ISSUE
#undef GL_CONS
#undef GT_ISSUE
#undef GT_CONS

    // write packed hi/lo rows (zeros for OOB rows -> GEMM reads no garbage)
    #pragma unroll
    for (int i = 0; i < 4; i++) {
      int nrow = wave * 4 + i;
      hAp[nrow * LDAF + (lane << 1)] = packhl(acc0[i]);
      hAp[nrow * LDAF + (lane << 1) + 1] = packhl(acc1[i]);
    }
  }
  __syncthreads();

  const int col = lane & 15;
  const int quad = lane >> 4;
  const int rbase = quad * 4;
  const int ch0 = wave * 16 + col;  // this wave's 16-channel tile
  const int aoff = quad * 8;

  // ---- phase 2: GEMM1 (hA @ W1 + b1, relu) -> back into hA ----
  {
    f32x4 a0 = {0.f, 0.f, 0.f, 0.f}, a1 = a0;
    #pragma unroll
    for (int q = 0; q < 4; q++) {
      int f0 = wave * 256 + q * 64 + lane;
      short8 b0h = Wh[f0], b0l = Wl[f0];
      const unsigned* r0 = &hAp[col * LDAF + q * 32 + aoff];
      const unsigned* r1 = &hAp[(16 + col) * LDAF + q * 32 + aoff];
      short8 a0h, a0l, a1h, a1l;
      unpack8(*(const uint4*)r0, *(const uint4*)(r0 + 4), a0h, a0l);
      unpack8(*(const uint4*)r1, *(const uint4*)(r1 + 4), a1h, a1l);
      a0 = __builtin_amdgcn_mfma_f32_16x16x32_bf16(a0h, b0h, a0, 0, 0, 0);
      a0 = __builtin_amdgcn_mfma_f32_16x16x32_bf16(a0l, b0h, a0, 0, 0, 0);
      a0 = __builtin_amdgcn_mfma_f32_16x16x32_bf16(a0h, b0l, a0, 0, 0, 0);
      a1 = __builtin_amdgcn_mfma_f32_16x16x32_bf16(a1h, b0h, a1, 0, 0, 0);
      a1 = __builtin_amdgcn_mfma_f32_16x16x32_bf16(a1l, b0h, a1, 0, 0, 0);
      a1 = __builtin_amdgcn_mfma_f32_16x16x32_bf16(a1h, b0l, a1, 0, 0, 0);
    }
    __syncthreads();  // all GEMM1 reads of hA complete
    float bb0 = b1[ch0];
    #pragma unroll
    for (int r = 0; r < 4; r++) {
      hAp[(rbase + r) * LDAF + ch0] = packhl(fmaxf(a0[r] + bb0, 0.0f));
      hAp[(16 + rbase + r) * LDAF + ch0] = packhl(fmaxf(a1[r] + bb0, 0.0f));
    }
  }
  __syncthreads();

  // ---- phase 3: GEMM2 (h1 @ W2 + b2, relu) -> back into hA ----
  {
    f32x4 a0 = {0.f, 0.f, 0.f, 0.f}, a1 = a0;
    #pragma unroll
    for (int q = 0; q < 4; q++) {
      int f0 = 2048 + wave * 256 + q * 64 + lane;  // gemm2 frags
      short8 b0h = Wh[f0], b0l = Wl[f0];
      const unsigned* r0 = &hAp[col * LDAF + q * 32 + aoff];
      const unsigned* r1 = &hAp[(16 + col) * LDAF + q * 32 + aoff];
      short8 a0h, a0l, a1h, a1l;
      unpack8(*(const uint4*)r0, *(const uint4*)(r0 + 4), a0h, a0l);
      unpack8(*(const uint4*)r1, *(const uint4*)(r1 + 4), a1h, a1l);
      a0 = __builtin_amdgcn_mfma_f32_16x16x32_bf16(a0h, b0h, a0, 0, 0, 0);
      a0 = __builtin_amdgcn_mfma_f32_16x16x32_bf16(a0l, b0h, a0, 0, 0, 0);
      a0 = __builtin_amdgcn_mfma_f32_16x16x32_bf16(a0h, b0l, a0, 0, 0, 0);
      a1 = __builtin_amdgcn_mfma_f32_16x16x32_bf16(a1h, b0h, a1, 0, 0, 0);
      a1 = __builtin_amdgcn_mfma_f32_16x16x32_bf16(a1l, b0h, a1, 0, 0, 0);
      a1 = __builtin_amdgcn_mfma_f32_16x16x32_bf16(a1h, b0l, a1, 0, 0, 0);
    }
    __syncthreads();  // all GEMM2 reads complete
    float bb0 = b2[ch0];
    #pragma unroll
    for (int r = 0; r < 4; r++) {
      hAp[(rbase + r) * LDAF + ch0] = packhl(fmaxf(a0[r] + bb0, 0.0f));
      hAp[(16 + rbase + r) * LDAF + ch0] = packhl(fmaxf(a1[r] + bb0, 0.0f));
    }
  }
  __syncthreads();

  // ---- phase 4: epilogue (h2 packed in hAp); first 256 threads compute ----
  float lsum = 0.0f, lsq = 0.0f;
  if (tid < 256) {
    const int c = tid & 127;
    const int yy = tid >> 7;
    if (out_bf) {
      #pragma unroll 4
      for (int i = 0; i < 16; i++) {
        int n = yy * 16 + i;
        int node = base + n;
        if (node < NNODES) {
          unsigned p = hAp[n * LDAF + c];
          out_bf[node * HID + c] = (unsigned short)(p & 0xFFFF);  // == f2bf(v)
          float v = upk(p);
          lsum += v;
          lsq += v * v;
        }
      }
    } else {
      int curg = -1;
      float pacc = 0.0f;
      for (int i = 0; i < 16; i++) {
        int n = yy * 16 + i;
        int node = base + n;
        if (node < NNODES) {
          float v = upk(hAp[n * LDAF + c]);
          lsum += v;
          lsq += v * v;
          int bg = batch[node];
          if (bg != curg) {
            if (curg >= 0) unsafeAtomicAdd(&gpool[curg * HID + c], pacc);
            curg = bg;
            pacc = 0.0f;
          }
          pacc += v;
        }
      }
      if (curg >= 0) unsafeAtomicAdd(&gpool[curg * HID + c], pacc);
    }
    if (tid >= 128) {  // stash yy=1 partials; combined below (halves atomics)
      red[tid - 128] = lsum;
      red[tid] = lsq;  // red[128..255]
    }
  }
  __syncthreads();
  if (tid < 128) {
    lsum += red[tid];
    lsq += red[128 + tid];
    unsafeAtomicAdd(&stats[tid], lsum);
    unsafeAtomicAdd(&stats[HID + tid], lsq);
  }
}

// ---------------------------------------------------------------------------
// out[g,c] = scl_c * gpool[g,c] + cnt_g * sh_c  (BN affine commutes with pool)
__device__ __forceinline__ int lbound(const int* __restrict__ arr, int n,
                                      int key) {
  int lo = 0, hi = n;
  while (lo < hi) {
    int mid = (lo + hi) >> 1;
    if (arr[mid] < key) lo = mid + 1; else hi = mid;
  }
  return lo;
}

__global__ __launch_bounds__(128) void finish_kernel(
    const float* __restrict__ gpool, const float* __restrict__ stats,
    const float* __restrict__ gam, const float* __restrict__ bet,
    const int* __restrict__ batch, float* __restrict__ out) {
  __shared__ int cnt_s;
  int g = blockIdx.x, c = threadIdx.x;
  if (c == 0)
    cnt_s = lbound(batch, NNODES, g + 1) - lbound(batch, NNODES, g);
  __syncthreads();
  float mu = stats[c] * (1.0f / NNODES);
  float var = stats[HID + c] * (1.0f / NNODES) - mu * mu;
  float scl = gam[c] * rsqrtf(var + BN_EPS);
  float sh = bet[c] - mu * scl;
  out[g * HID + c] = fmaf(gpool[g * HID + c], scl, (float)cnt_s * sh);
}

// ---------------------------------------------------------------------------
extern "C" void kernel_launch(void* const* d_in, const int* in_sizes, int n_in,
                              void* d_out, int out_size, void* d_ws, size_t ws_size,
                              hipStream_t stream) {
  const int* x_idx = (const int*)d_in[0];
  const int* eidx = (const int*)d_in[1];   // [2, E]: src row then dst row
  const int* eattr = (const int*)d_in[2];
  const int* batch = (const int*)d_in[3];
  const float* node_emb = (const float*)d_in[4];
  const float* edge_emb = (const float*)d_in[5];
  const float* W1 = (const float*)d_in[6];
  const float* b1 = (const float*)d_in[7];
  const float* W2 = (const float*)d_in[8];
  const float* b2 = (const float*)d_in[9];
  const float* bn_g = (const float*)d_in[10];
  const float* bn_b = (const float*)d_in[11];
  float* out = (float*)d_out;

  const size_t nfeat = (size_t)NNODES * HID;
  unsigned short* h2bf = (unsigned short*)d_ws;  // [N,H] bf16
  float* stats0 = (float*)(h2bf + nfeat);        // [2,H]
  float* stats1 = stats0 + 2 * HID;              // [2,H]
  float* gpool = stats1 + 2 * HID;               // [G,H]
  int* cnt = (int*)(gpool + NGRAPHS * HID);      // [N]   (zeroed with stats)
  int* eout = cnt + NNODES;                      // [N*CAP]
  unsigned short* Wpk = (unsigned short*)(eout + (size_t)NNODES * CAP);
  unsigned* msgTg = (unsigned*)(Wpk + 131072);   // [76*64] bf16x2
  unsigned* typeT = msgTg + 76 * 64;             // [19*64] bf16x2
  size_t needed = (size_t)((char*)(typeT + 19 * 64) - (char*)d_ws);
  if (ws_size < needed) return;  // fails validation loudly, doesn't corrupt

  // zero stats0, stats1, gpool, cnt in one shot (contiguous)
  hipMemsetAsync(stats0, 0, (4 * HID + NGRAPHS * HID + NNODES) * sizeof(int),
                 stream);

  prep_kernel<<<1024, 256, 0, stream>>>(x_idx, node_emb, eidx, eattr, cnt,
                                        eout, W1, W2, Wpk, msgTg, typeT,
                                        edge_emb);

  const short8* Wfh = (const short8*)Wpk;  // 8192 frags (hi)
  const short8* Wfl = Wfh + 8192;          // 8192 frags (lo)
  const size_t smemsz = (size_t)NT * LDAF * 4 + 4 * HID * 4;  // hAp + sheL/red
  // layer 0: self from typeT[x_idx[node]], msgs from msgTg -> h2bf, stats0
  gine_mlp_kernel<true><<<GRID_GINE, 512, smemsz, stream>>>(
      (const unsigned short*)typeT, x_idx, nullptr, nullptr, nullptr, cnt,
      eout, msgTg, edge_emb, Wfh + 0 * 2048, Wfl + 0 * 2048, b1, b2, h2bf,
      stats0, nullptr, nullptr);
  // layer 1: in = h2bf with BN(layer0) folded, out -> gpool + stats1
  gine_mlp_kernel<false><<<GRID_GINE, 512, smemsz, stream>>>(
      h2bf, nullptr, stats0, bn_g, bn_b, cnt, eout, msgTg, edge_emb,
      Wfh + 2 * 2048, Wfl + 2 * 2048, b1 + HID, b2 + HID, nullptr, stats1,
      batch, gpool);
  // final: out = scl*gpool + cnt*sh
  finish_kernel<<<NGRAPHS, 128, 0, stream>>>(gpool, stats1, bn_g + HID,
                                             bn_b + HID, batch, out);
}